// Round 2
// baseline (1383.217 us; speedup 1.0000x reference)
//
#include <hip/hip_runtime.h>
#include <cstdint>
#include <cstddef>

// Problem constants
#define B_   32
#define L_   1024
#define E_   512
#define D_   512
#define M_   (B_ * L_)   // 32768 rows (b*L + l)
#define N8D  4096        // 8*D columns of U
#define SCALEF 1.4142135623730951f

typedef unsigned short u16;
typedef __bf16 bf16x8 __attribute__((ext_vector_type(8)));
typedef unsigned short u16x8 __attribute__((ext_vector_type(8)));
typedef unsigned short u16x4 __attribute__((ext_vector_type(4)));
typedef float f32x4 __attribute__((ext_vector_type(4)));

__device__ __forceinline__ float bf2f(u16 u) {
    union { unsigned int i; float f; } v; v.i = ((unsigned int)u) << 16; return v.f;
}
__device__ __forceinline__ u16 f2bf(float x) {
    union { float f; unsigned int i; } v; v.f = x;
    unsigned int r = (v.i + 0x7fffu + ((v.i >> 16) & 1u)) >> 16;
    return (u16)r;
}

// ---------------- transpose W (R,C) f32 -> (C,R) bf16 ----------------
__global__ __launch_bounds__(256) void transpose_w(const float* __restrict__ in,
                                                   u16* __restrict__ out,
                                                   int R, int C) {
    __shared__ u16 tile[32][33];
    int bx = blockIdx.x * 32;  // col base in input
    int by = blockIdx.y * 32;  // row base in input
    int tx = threadIdx.x & 31;
    int ty = threadIdx.x >> 5; // 0..7
#pragma unroll
    for (int i = 0; i < 32; i += 8)
        tile[ty + i][tx] = f2bf(in[(size_t)(by + ty + i) * C + bx + tx]);
    __syncthreads();
#pragma unroll
    for (int i = 0; i < 32; i += 8)
        out[(size_t)(bx + ty + i) * R + by + tx] = tile[tx][ty + i];
}

// ---------------- GEMM: U(M,4096) = A(M,K) * BT(4096,K)^T ----------------
// A is f32 (layer 0, converted in staging) or bf16 (layer 1). BT bf16.
// Output U stored bf16 with component-interleaved layout:
//   logical col n -> offset (n>>11)*2048 + (n&511)*4 + ((n>>9)&3)
// so the scan reads {xt,fp,rp,xp} for one (dir,d) as one contiguous u16x4.
template<bool A_F32>
__global__ __launch_bounds__(256) void gemm_bt(const void* __restrict__ Av,
                                               const u16* __restrict__ BT,
                                               u16* __restrict__ U, int K) {
    __shared__ __align__(16) u16 As[128][40];  // +8 pad breaks bank conflicts
    __shared__ __align__(16) u16 Bs[128][40];
    const int t    = threadIdx.x;
    const int bn   = blockIdx.x * 128;
    const int bm   = blockIdx.y * 128;
    const int lane = t & 63;
    const int wave = t >> 6;
    const int wm   = (wave >> 1) * 64;
    const int wn   = (wave & 1) * 64;
    const int qm   = lane & 15;
    const int quad = lane >> 4;

    f32x4 acc[4][4];
#pragma unroll
    for (int i = 0; i < 4; ++i)
#pragma unroll
        for (int j = 0; j < 4; ++j)
            acc[i][j] = (f32x4)(0.0f);

    const int srow = t >> 2;       // 0..63
    const int scol = (t & 3) * 8;  // 0,8,16,24

    for (int k0 = 0; k0 < K; k0 += 32) {
        __syncthreads();
#pragma unroll
        for (int h = 0; h < 2; ++h) {
            int r = srow + h * 64;
            u16x8 av;
            if (A_F32) {
                const float* p = (const float*)Av + (size_t)(bm + r) * K + k0 + scol;
                f32x4 v0 = *(const f32x4*)p;
                f32x4 v1 = *(const f32x4*)(p + 4);
#pragma unroll
                for (int q = 0; q < 4; ++q) { av[q] = f2bf(v0[q]); av[4 + q] = f2bf(v1[q]); }
            } else {
                av = *(const u16x8*)((const u16*)Av + (size_t)(bm + r) * K + k0 + scol);
            }
            *(u16x8*)(&As[r][scol]) = av;
            u16x8 bv = *(const u16x8*)(BT + (size_t)(bn + r) * K + k0 + scol);
            *(u16x8*)(&Bs[r][scol]) = bv;
        }
        __syncthreads();

        bf16x8 a[4], b[4];
#pragma unroll
        for (int i = 0; i < 4; ++i)
            a[i] = *(const bf16x8*)(&As[wm + i * 16 + qm][quad * 8]);
#pragma unroll
        for (int j = 0; j < 4; ++j)
            b[j] = *(const bf16x8*)(&Bs[wn + j * 16 + qm][quad * 8]);
#pragma unroll
        for (int i = 0; i < 4; ++i)
#pragma unroll
            for (int j = 0; j < 4; ++j)
                acc[i][j] = __builtin_amdgcn_mfma_f32_16x16x32_bf16(a[i], b[j], acc[i][j], 0, 0, 0);
    }

    // epilogue: C/D layout col=lane&15, row=quad*4+reg; interleaved U store
    int coff[4];
#pragma unroll
    for (int j = 0; j < 4; ++j) {
        int n = bn + wn + j * 16 + qm;
        coff[j] = (n >> 11) * 2048 + (n & 511) * 4 + ((n >> 9) & 3);
    }
#pragma unroll
    for (int i = 0; i < 4; ++i) {
        int row0 = bm + wm + i * 16 + quad * 4;
#pragma unroll
        for (int j = 0; j < 4; ++j) {
#pragma unroll
            for (int r = 0; r < 4; ++r)
                U[(size_t)(row0 + r) * N8D + coff[j]] = f2bf(acc[i][j][r]);
        }
    }
}

// ---------------- SRU scan: one thread per (b, dir, d) ----------------
// U (interleaved): (b*L+l)*4096 + dir*2048 + d*4 + {0:xt,1:fp,2:rp,3:xp}
// H: (b*L+l)*1024 + dir*512 + d ; C: b*1024 + dir*512 + d
template<bool OUT_F32>
__global__ __launch_bounds__(256) void sru_scan(const u16* __restrict__ U,
                                                const float* __restrict__ vf,
                                                const float* __restrict__ vr,
                                                const float* __restrict__ bfv,
                                                const float* __restrict__ brv,
                                                void* __restrict__ Hv,
                                                void* __restrict__ Cv) {
    int gid = blockIdx.x * blockDim.x + threadIdx.x;  // 0..32767
    int d   = gid & (D_ - 1);
    int dir = (gid >> 9) & 1;
    int b   = gid >> 10;
    int ch  = dir * D_ + d;

    float vf_v = vf[ch];
    float vr_v = vr[ch];
    float bf_v = bfv[ch];
    float br_v = brv[ch];

    const u16* Ub = U + (size_t)b * L_ * N8D + dir * 2048 + d * 4;

    float c = 0.0f;
    if (dir == 0) {
#pragma unroll 8
        for (int l = 0; l < L_; ++l) {
            u16x4 q = *(const u16x4*)(Ub + (size_t)l * N8D);
            float xt = bf2f(q[0]), fp = bf2f(q[1]), rp = bf2f(q[2]), xp = bf2f(q[3]);
            float f = 1.0f / (1.0f + __expf(-(fp + vf_v * c + bf_v)));
            float r = 1.0f / (1.0f + __expf(-(rp + vr_v * c + br_v)));
            c = f * c + (1.0f - f) * xt;
            float h = r * c + (1.0f - r) * xp * SCALEF;
            size_t hi = (size_t)(b * L_ + l) * 1024 + ch;
            if (OUT_F32) ((float*)Hv)[hi] = h; else ((u16*)Hv)[hi] = f2bf(h);
        }
    } else {
#pragma unroll 8
        for (int l = L_ - 1; l >= 0; --l) {
            u16x4 q = *(const u16x4*)(Ub + (size_t)l * N8D);
            float xt = bf2f(q[0]), fp = bf2f(q[1]), rp = bf2f(q[2]), xp = bf2f(q[3]);
            float f = 1.0f / (1.0f + __expf(-(fp + vf_v * c + bf_v)));
            float r = 1.0f / (1.0f + __expf(-(rp + vr_v * c + br_v)));
            c = f * c + (1.0f - f) * xt;
            float h = r * c + (1.0f - r) * xp * SCALEF;
            size_t hi = (size_t)(b * L_ + l) * 1024 + ch;
            if (OUT_F32) ((float*)Hv)[hi] = h; else ((u16*)Hv)[hi] = f2bf(h);
        }
    }
    if (OUT_F32) ((float*)Cv)[b * 1024 + ch] = c;
    else         ((u16*)Cv)[b * 1024 + ch]  = f2bf(c);
}

// ---------------- launch ----------------
extern "C" void kernel_launch(void* const* d_in, const int* in_sizes, int n_in,
                              void* d_out, int out_size, void* d_ws, size_t ws_size,
                              hipStream_t stream) {
    (void)in_sizes; (void)n_in; (void)out_size; (void)ws_size;

    const float* seqs = (const float*)d_in[0];
    const float* W0   = (const float*)d_in[1];
    const float* vf0  = (const float*)d_in[2];
    const float* vr0  = (const float*)d_in[3];
    const float* bf0  = (const float*)d_in[4];
    const float* br0  = (const float*)d_in[5];
    const float* W1   = (const float*)d_in[6];
    const float* vf1  = (const float*)d_in[7];
    const float* vr1  = (const float*)d_in[8];
    const float* bf1  = (const float*)d_in[9];
    const float* br1  = (const float*)d_in[10];
    // d_in[11] = lengths : unused by the reference

    float* out = (float*)d_out;  // [c1: 32*1024 f32][out1: 32*1024*1024 f32]
    char* ws = (char*)d_ws;

    const size_t U_BYTES  = (size_t)M_ * N8D * 2;        // 268435456
    const size_t H_BYTES  = (size_t)M_ * 1024 * 2;       // 67108864
    const size_t W0T_B    = (size_t)4096 * 512 * 2;      // 4194304
    const size_t W1T_B    = (size_t)4096 * 1024 * 2;     // 8388608

    u16* U   = (u16*)(ws);
    u16* H0  = (u16*)(ws + U_BYTES);
    u16* W0T = (u16*)(ws + U_BYTES + H_BYTES);
    u16* W1T = (u16*)(ws + U_BYTES + H_BYTES + W0T_B);
    u16* Cd  = (u16*)(ws + U_BYTES + H_BYTES + W0T_B + W1T_B);  // dummy c, layer 0

    // W0 (512,4096) f32 -> W0T (4096,512) bf16 ; W1 (1024,4096) -> W1T (4096,1024)
    transpose_w<<<dim3(4096 / 32, 512 / 32), 256, 0, stream>>>(W0, W0T, 512, 4096);
    transpose_w<<<dim3(4096 / 32, 1024 / 32), 256, 0, stream>>>(W1, W1T, 1024, 4096);

    // Layer 0: A = seqs (f32), K=512
    gemm_bt<true><<<dim3(N8D / 128, M_ / 128), 256, 0, stream>>>((const void*)seqs, W0T, U, 512);
    sru_scan<false><<<dim3(M_ / 256), 256, 0, stream>>>(U, vf0, vr0, bf0, br0, (void*)H0, (void*)Cd);

    // Layer 1: A = H0 (bf16), K=1024
    gemm_bt<false><<<dim3(N8D / 128, M_ / 128), 256, 0, stream>>>((const void*)H0, W1T, U, 1024);
    sru_scan<true><<<dim3(M_ / 256), 256, 0, stream>>>(U, vf1, vr1, bf1, br1,
                                                       (void*)(out + B_ * 1024), (void*)out);
}

// Round 3
// 1089.774 us; speedup vs baseline: 1.2693x; 1.2693x over previous
//
#include <hip/hip_runtime.h>
#include <cstdint>
#include <cstddef>

// Problem constants
#define B_   32
#define L_   1024
#define D_   512
#define M_   (B_ * L_)   // 32768 rows (b*L + l)
#define N8D  4096        // 8*D columns of U
#define SCALEF 1.4142135623730951f

typedef unsigned short u16;
typedef __bf16 bf16x8 __attribute__((ext_vector_type(8)));
typedef unsigned short u16x8 __attribute__((ext_vector_type(8)));
typedef unsigned short u16x4 __attribute__((ext_vector_type(4)));
typedef float f32x4 __attribute__((ext_vector_type(4)));

__device__ __forceinline__ float bf2f(u16 u) {
    union { unsigned int i; float f; } v; v.i = ((unsigned int)u) << 16; return v.f;
}
__device__ __forceinline__ u16 f2bf(float x) {
    union { float f; unsigned int i; } v; v.f = x;
    unsigned int r = (v.i + 0x7fffu + ((v.i >> 16) & 1u)) >> 16;
    return (u16)r;
}

// async global->LDS, 16 bytes per lane. LDS dest must be wave-uniform base + lane*16.
__device__ __forceinline__ void gl2lds16(const u16* g, u16* l) {
    __builtin_amdgcn_global_load_lds(
        (const __attribute__((address_space(1))) void*)g,
        (__attribute__((address_space(3))) void*)l, 16, 0, 0);
}

// ---------------- f32 -> bf16 convert (seqs), 8 elems/thread ----------------
__global__ __launch_bounds__(256) void f32_to_bf16(const float* __restrict__ in,
                                                   u16* __restrict__ out) {
    size_t i = ((size_t)blockIdx.x * 256 + threadIdx.x) * 8;
    f32x4 v0 = *(const f32x4*)(in + i);
    f32x4 v1 = *(const f32x4*)(in + i + 4);
    u16x8 o;
#pragma unroll
    for (int q = 0; q < 4; ++q) { o[q] = f2bf(v0[q]); o[4 + q] = f2bf(v1[q]); }
    *(u16x8*)(out + i) = o;
}

// ---------------- transpose W (K,4096) f32 -> WT bf16, rows PERMUTED ----------
// Physical WT row p holds logical W column n, with
//   n = dir*2048 + comp*512 + d  ->  p = dir*2048 + d*4 + comp
// so GEMM output column p is already in scan-interleaved order.
__global__ __launch_bounds__(256) void transpose_w(const float* __restrict__ in,
                                                   u16* __restrict__ out,
                                                   int R, int C) {
    __shared__ u16 tile[32][33];
    int bx = blockIdx.x * 32;  // col base in input (n)
    int by = blockIdx.y * 32;  // row base in input (k)
    int tx = threadIdx.x & 31;
    int ty = threadIdx.x >> 5; // 0..7
#pragma unroll
    for (int i = 0; i < 32; i += 8)
        tile[ty + i][tx] = f2bf(in[(size_t)(by + ty + i) * C + bx + tx]);
    __syncthreads();
#pragma unroll
    for (int i = 0; i < 32; i += 8) {
        int n = bx + ty + i;
        int p = (n >> 11) * 2048 + ((n & 511) << 2) + ((n >> 9) & 3);
        out[(size_t)p * R + by + tx] = tile[tx][ty + i];
    }
}

// ---------------- GEMM: U(M,4096) = A(M,K) * BT(4096,K)^T, all bf16 ----------
// m97 structure: 128x128 tile, BK=32, global_load_lds width 16, unpadded LDS.
__global__ __launch_bounds__(256) void gemm_bt(const u16* __restrict__ A,
                                               const u16* __restrict__ BT,
                                               u16* __restrict__ U, int K) {
    __shared__ __align__(16) u16 As[128][32];
    __shared__ __align__(16) u16 Bs[128][32];
    const int t    = threadIdx.x;
    const int bn   = blockIdx.x * 128;
    const int bm   = blockIdx.y * 128;
    const int lane = t & 63;
    const int wave = t >> 6;
    const int wm   = (wave >> 1) * 64;
    const int wn   = (wave & 1) * 64;
    const int qm   = lane & 15;
    const int quad = lane >> 4;

    f32x4 acc[4][4];
#pragma unroll
    for (int i = 0; i < 4; ++i)
#pragma unroll
        for (int j = 0; j < 4; ++j)
            acc[i][j] = (f32x4)(0.0f);

    // staging addresses: thread t covers row t/4, 16B chunk (t&3) of a 128x32 tile
    const int srow = t >> 2;        // 0..63
    const int scol = (t & 3) * 8;   // element offset
    const u16* ag = A  + (size_t)(bm + srow) * K + scol;
    const u16* bg = BT + (size_t)(bn + srow) * K + scol;
    u16* al = &As[srow][scol];      // LDS byte offset = t*16
    u16* bl = &Bs[srow][scol];
    const size_t gstep = (size_t)64 * K;

    for (int k0 = 0; k0 < K; k0 += 32) {
        __syncthreads();
        gl2lds16(ag + k0,         al);
        gl2lds16(ag + k0 + gstep, al + 64 * 32);
        gl2lds16(bg + k0,         bl);
        gl2lds16(bg + k0 + gstep, bl + 64 * 32);
        __syncthreads();

        bf16x8 a[4], b[4];
#pragma unroll
        for (int i = 0; i < 4; ++i)
            a[i] = *(const bf16x8*)(&As[wm + i * 16 + qm][quad * 8]);
#pragma unroll
        for (int j = 0; j < 4; ++j)
            b[j] = *(const bf16x8*)(&Bs[wn + j * 16 + qm][quad * 8]);
#pragma unroll
        for (int i = 0; i < 4; ++i)
#pragma unroll
            for (int j = 0; j < 4; ++j)
                acc[i][j] = __builtin_amdgcn_mfma_f32_16x16x32_bf16(a[i], b[j], acc[i][j], 0, 0, 0);
    }

    // epilogue: C/D layout col=lane&15, row=quad*4+reg; plain contiguous cols
#pragma unroll
    for (int i = 0; i < 4; ++i) {
        int row0 = bm + wm + i * 16 + quad * 4;
#pragma unroll
        for (int j = 0; j < 4; ++j) {
            int col = bn + wn + j * 16 + qm;
#pragma unroll
            for (int r = 0; r < 4; ++r)
                U[(size_t)(row0 + r) * N8D + col] = f2bf(acc[i][j][r]);
        }
    }
}

// ---------------- SRU scan: one thread per (b, dir, d) ----------------
// U (interleaved): (b*L+l)*4096 + dir*2048 + d*4 + {0:xt,1:fp,2:rp,3:xp}
// H: (b*L+l)*1024 + dir*512 + d ; C: b*1024 + dir*512 + d
template<bool OUT_F32>
__global__ __launch_bounds__(256) void sru_scan(const u16* __restrict__ U,
                                                const float* __restrict__ vf,
                                                const float* __restrict__ vr,
                                                const float* __restrict__ bfv,
                                                const float* __restrict__ brv,
                                                void* __restrict__ Hv,
                                                void* __restrict__ Cv) {
    int gid = blockIdx.x * blockDim.x + threadIdx.x;  // 0..32767
    int d   = gid & (D_ - 1);
    int dir = (gid >> 9) & 1;   // uniform within a block
    int b   = gid >> 10;
    int ch  = dir * D_ + d;

    float vf_v = vf[ch];
    float vr_v = vr[ch];
    float bf_v = bfv[ch];
    float br_v = brv[ch];

    const u16* Ub = U + (size_t)b * L_ * N8D + dir * 2048 + d * 4;
    float* Hf = (float*)Hv;
    u16*   Hh = (u16*)Hv;
    size_t hbase = (size_t)b * L_ * 1024 + ch;

    float c = 0.0f;
    for (int l0 = 0; l0 < L_; l0 += 16) {
        u16x4 q[16];
#pragma unroll
        for (int i = 0; i < 16; ++i) {
            int l = dir ? (L_ - 1 - (l0 + i)) : (l0 + i);
            q[i] = *(const u16x4*)(Ub + (size_t)l * N8D);
        }
#pragma unroll
        for (int i = 0; i < 16; ++i) {
            int l = dir ? (L_ - 1 - (l0 + i)) : (l0 + i);
            float xt = bf2f(q[i][0]), fp = bf2f(q[i][1]);
            float rp = bf2f(q[i][2]), xp = bf2f(q[i][3]);
            float f = 1.0f / (1.0f + __expf(-(fp + vf_v * c + bf_v)));
            float r = 1.0f / (1.0f + __expf(-(rp + vr_v * c + br_v)));
            c = f * c + (1.0f - f) * xt;
            float h = r * c + (1.0f - r) * xp * SCALEF;
            size_t hi = hbase + (size_t)l * 1024;
            if (OUT_F32) Hf[hi] = h; else Hh[hi] = f2bf(h);
        }
    }
    if (OUT_F32) ((float*)Cv)[b * 1024 + ch] = c;
    else         ((u16*)Cv)[b * 1024 + ch]  = f2bf(c);
}

// ---------------- launch ----------------
extern "C" void kernel_launch(void* const* d_in, const int* in_sizes, int n_in,
                              void* d_out, int out_size, void* d_ws, size_t ws_size,
                              hipStream_t stream) {
    (void)in_sizes; (void)n_in; (void)out_size; (void)ws_size;

    const float* seqs = (const float*)d_in[0];
    const float* W0   = (const float*)d_in[1];
    const float* vf0  = (const float*)d_in[2];
    const float* vr0  = (const float*)d_in[3];
    const float* bf0  = (const float*)d_in[4];
    const float* br0  = (const float*)d_in[5];
    const float* W1   = (const float*)d_in[6];
    const float* vf1  = (const float*)d_in[7];
    const float* vr1  = (const float*)d_in[8];
    const float* bf1  = (const float*)d_in[9];
    const float* br1  = (const float*)d_in[10];
    // d_in[11] = lengths : unused by the reference

    float* out = (float*)d_out;  // [c1: 32*1024 f32][out1: 32*1024*1024 f32]
    char* ws = (char*)d_ws;

    const size_t U_BYTES  = (size_t)M_ * N8D * 2;        // 268435456
    const size_t H_BYTES  = (size_t)M_ * 1024 * 2;       // 67108864
    const size_t W0T_B    = (size_t)4096 * 512 * 2;      // 4194304
    const size_t W1T_B    = (size_t)4096 * 1024 * 2;     // 8388608

    u16* U   = (u16*)(ws);
    u16* H0  = (u16*)(ws + U_BYTES);              // also holds seqs_bf16 before scan0
    u16* S16 = H0;                                 // 33.5MB, dead after gemm0
    u16* W0T = (u16*)(ws + U_BYTES + H_BYTES);
    u16* W1T = (u16*)(ws + U_BYTES + H_BYTES + W0T_B);
    u16* Cd  = (u16*)(ws + U_BYTES + H_BYTES + W0T_B + W1T_B);  // dummy c, layer 0

    // seqs f32 -> bf16 (16,777,216 elems / 8 per thread / 256 per block)
    f32_to_bf16<<<dim3(M_ * 512 / 8 / 256), 256, 0, stream>>>(seqs, S16);

    // W0 (512,4096) f32 -> W0T bf16 (permuted rows); W1 (1024,4096) -> W1T
    transpose_w<<<dim3(4096 / 32, 512 / 32), 256, 0, stream>>>(W0, W0T, 512, 4096);
    transpose_w<<<dim3(4096 / 32, 1024 / 32), 256, 0, stream>>>(W1, W1T, 1024, 4096);

    // Layer 0: A = seqs_bf16, K=512
    gemm_bt<<<dim3(N8D / 128, M_ / 128), 256, 0, stream>>>(S16, W0T, U, 512);
    sru_scan<false><<<dim3(M_ / 256), 256, 0, stream>>>(U, vf0, vr0, bf0, br0, (void*)H0, (void*)Cd);

    // Layer 1: A = H0 (bf16), K=1024
    gemm_bt<<<dim3(N8D / 128, M_ / 128), 256, 0, stream>>>(H0, W1T, U, 1024);
    sru_scan<true><<<dim3(M_ / 256), 256, 0, stream>>>(U, vf1, vr1, bf1, br1,
                                                       (void*)(out + B_ * 1024), (void*)out);
}

// Round 4
// 950.676 us; speedup vs baseline: 1.4550x; 1.1463x over previous
//
#include <hip/hip_runtime.h>
#include <cstdint>
#include <cstddef>

// Problem constants
#define B_   32
#define L_   1024
#define D_   512
#define M_   (B_ * L_)   // 32768 rows (b*L + l)
#define N8D  4096        // 8*D columns of U
#define SCALEF 1.4142135623730951f
#define LOG2E 1.4426950408889634f

typedef unsigned short u16;
typedef __bf16 bf16x8 __attribute__((ext_vector_type(8)));
typedef unsigned short u16x8 __attribute__((ext_vector_type(8)));
typedef unsigned short u16x4 __attribute__((ext_vector_type(4)));
typedef float f32x4 __attribute__((ext_vector_type(4)));

__device__ __forceinline__ float bf2f(u16 u) {
    union { unsigned int i; float f; } v; v.i = ((unsigned int)u) << 16; return v.f;
}
__device__ __forceinline__ u16 f2bf(float x) {
    union { float f; unsigned int i; } v; v.f = x;
    unsigned int r = (v.i + 0x7fffu + ((v.i >> 16) & 1u)) >> 16;
    return (u16)r;
}
// fast sigmoid: v_exp_f32 + v_rcp_f32 (≈1 ulp f32 — far below bf16 noise)
__device__ __forceinline__ float sigmoid_fast(float z) {
    return __builtin_amdgcn_rcpf(1.0f + __builtin_amdgcn_exp2f(-LOG2E * z));
}

// async global->LDS, 16 bytes per lane. LDS dest = wave-uniform base + lane*16.
__device__ __forceinline__ void gl2lds16(const u16* g, u16* l) {
    __builtin_amdgcn_global_load_lds(
        (const __attribute__((address_space(1))) void*)g,
        (__attribute__((address_space(3))) void*)l, 16, 0, 0);
}

// ---------------- f32 -> bf16 convert (seqs), 8 elems/thread ----------------
__global__ __launch_bounds__(256) void f32_to_bf16(const float* __restrict__ in,
                                                   u16* __restrict__ out) {
    size_t i = ((size_t)blockIdx.x * 256 + threadIdx.x) * 8;
    f32x4 v0 = *(const f32x4*)(in + i);
    f32x4 v1 = *(const f32x4*)(in + i + 4);
    u16x8 o;
#pragma unroll
    for (int q = 0; q < 4; ++q) { o[q] = f2bf(v0[q]); o[4 + q] = f2bf(v1[q]); }
    *(u16x8*)(out + i) = o;
}

// ---------------- transpose W (K,4096) f32 -> WT bf16, rows PERMUTED ----------
// Physical WT row p holds logical W column n:  n = dir*2048 + comp*512 + d
//   -> p = dir*2048 + d*4 + comp   (GEMM output columns land scan-interleaved)
__global__ __launch_bounds__(256) void transpose_w(const float* __restrict__ in,
                                                   u16* __restrict__ out,
                                                   int R, int C) {
    __shared__ u16 tile[32][33];
    int bx = blockIdx.x * 32;
    int by = blockIdx.y * 32;
    int tx = threadIdx.x & 31;
    int ty = threadIdx.x >> 5;
#pragma unroll
    for (int i = 0; i < 32; i += 8)
        tile[ty + i][tx] = f2bf(in[(size_t)(by + ty + i) * C + bx + tx]);
    __syncthreads();
#pragma unroll
    for (int i = 0; i < 32; i += 8) {
        int n = bx + ty + i;
        int p = (n >> 11) * 2048 + ((n & 511) << 2) + ((n >> 9) & 3);
        out[(size_t)p * R + by + tx] = tile[tx][ty + i];
    }
}

// ---------------- GEMM: U(M,4096) = A(M,K) * BT(4096,K)^T, all bf16 ----------
// m97 structure + XOR bank-swizzle: LDS position (row, c) holds global chunk
// c ^ ((row>>1)&3); fragment reads then hit exactly 2 lanes/bank (free).
__global__ __launch_bounds__(256) void gemm_bt(const u16* __restrict__ A,
                                               const u16* __restrict__ BT,
                                               u16* __restrict__ U, int K) {
    __shared__ __align__(16) u16 As[128][32];
    __shared__ __align__(16) u16 Bs[128][32];
    const int t    = threadIdx.x;
    const int bn   = blockIdx.x * 128;
    const int bm   = blockIdx.y * 128;
    const int lane = t & 63;
    const int wave = t >> 6;
    const int wm   = (wave >> 1) * 64;
    const int wn   = (wave & 1) * 64;
    const int qm   = lane & 15;
    const int quad = lane >> 4;

    f32x4 acc[4][4];
#pragma unroll
    for (int i = 0; i < 4; ++i)
#pragma unroll
        for (int j = 0; j < 4; ++j)
            acc[i][j] = (f32x4)(0.0f);

    // staging: thread t owns LDS (row=t>>2, chunk=t&3) -> loads global chunk
    // (t&3) ^ ((row>>1)&3).  Row+64 has the same swizzle ((+64>>1)&3 == +0).
    const int srow = t >> 2;
    const int c4   = t & 3;
    const int gcol = (c4 ^ ((srow >> 1) & 3)) * 8;
    const u16* ag = A  + (size_t)(bm + srow) * K + gcol;
    const u16* bg = BT + (size_t)(bn + srow) * K + gcol;
    u16* al = &As[srow][c4 * 8];   // LDS byte offset = t*16
    u16* bl = &Bs[srow][c4 * 8];
    const size_t gstep = (size_t)64 * K;

    // fragment-read swizzled chunk position (same for A and B rows)
    const int psw = (quad ^ ((qm >> 1) & 3)) * 8;

    for (int k0 = 0; k0 < K; k0 += 32) {
        __syncthreads();
        gl2lds16(ag + k0,         al);
        gl2lds16(ag + k0 + gstep, al + 64 * 32);
        gl2lds16(bg + k0,         bl);
        gl2lds16(bg + k0 + gstep, bl + 64 * 32);
        __syncthreads();

        bf16x8 a[4], b[4];
#pragma unroll
        for (int i = 0; i < 4; ++i)
            a[i] = *(const bf16x8*)(&As[wm + i * 16 + qm][psw]);
#pragma unroll
        for (int j = 0; j < 4; ++j)
            b[j] = *(const bf16x8*)(&Bs[wn + j * 16 + qm][psw]);
#pragma unroll
        for (int i = 0; i < 4; ++i)
#pragma unroll
            for (int j = 0; j < 4; ++j)
                acc[i][j] = __builtin_amdgcn_mfma_f32_16x16x32_bf16(a[i], b[j], acc[i][j], 0, 0, 0);
    }

    // epilogue: C/D layout col=lane&15, row=quad*4+reg
#pragma unroll
    for (int i = 0; i < 4; ++i) {
        int row0 = bm + wm + i * 16 + quad * 4;
#pragma unroll
        for (int j = 0; j < 4; ++j) {
            int col = bn + wn + j * 16 + qm;
#pragma unroll
            for (int r = 0; r < 4; ++r)
                U[(size_t)(row0 + r) * N8D + col] = f2bf(acc[i][j][r]);
        }
    }
}

// ---------------- SRU scan: one thread per (b, dir, d) ----------------
// U (interleaved): (b*L+l)*4096 + dir*2048 + d*4 + {0:xt,1:fp,2:rp,3:xp}
// H: (b*L+l)*1024 + dir*512 + d ; C: b*1024 + dir*512 + d
// PF=32 ping-pong prefetch: batch t+1 loads issue BEFORE batch t compute, so
// vmcnt waits for loads never drain the (shared-counter) h-stores.
template<bool OUT_F32>
__global__ __launch_bounds__(256) void sru_scan(const u16* __restrict__ U,
                                                const float* __restrict__ vf,
                                                const float* __restrict__ vr,
                                                const float* __restrict__ bfv,
                                                const float* __restrict__ brv,
                                                void* __restrict__ Hv,
                                                void* __restrict__ Cv) {
    constexpr int PF = 32;
    constexpr int NB = L_ / PF;  // 32 batches

    int gid = blockIdx.x * blockDim.x + threadIdx.x;  // 0..32767
    int d   = gid & (D_ - 1);
    int dir = (gid >> 9) & 1;   // uniform within a block
    int b   = gid >> 10;
    int ch  = dir * D_ + d;

    const float vf_v = vf[ch];
    const float vr_v = vr[ch];
    const float bf_v = bfv[ch];
    const float br_v = brv[ch];

    // direction-adjusted start pointers + signed element steps
    const ptrdiff_t ustep = dir ? -(ptrdiff_t)N8D : (ptrdiff_t)N8D;
    const ptrdiff_t hstep = dir ? -(ptrdiff_t)1024 : (ptrdiff_t)1024;
    const u16* p0 = U + (size_t)b * L_ * N8D + dir * 2048 + d * 4
                      + (dir ? (size_t)(L_ - 1) * N8D : 0);
    const size_t hstart = (size_t)b * L_ * 1024 + ch + (dir ? (size_t)(L_ - 1) * 1024 : 0);
    float* Hf = (float*)Hv + hstart;
    u16*   Hh = (u16*)Hv + hstart;

    float c = 0.0f;

    auto loadB = [&](u16x4 (&buf)[PF], int tb) {
        const u16* base = p0 + (ptrdiff_t)tb * PF * ustep;
#pragma unroll
        for (int i = 0; i < PF; ++i)
            buf[i] = *(const u16x4*)(base + (ptrdiff_t)i * ustep);
    };
    auto compStore = [&](u16x4 (&buf)[PF], int tb) {
        const ptrdiff_t hb = (ptrdiff_t)tb * PF * hstep;
#pragma unroll
        for (int i = 0; i < PF; ++i) {
            float xt = bf2f(buf[i][0]), fp = bf2f(buf[i][1]);
            float rp = bf2f(buf[i][2]), xp = bf2f(buf[i][3]);
            float f = sigmoid_fast(fp + vf_v * c + bf_v);
            float r = sigmoid_fast(rp + vr_v * c + br_v);
            c = f * (c - xt) + xt;                 // f*c + (1-f)*xt
            float xs = xp * SCALEF;
            float h  = r * (c - xs) + xs;          // r*c + (1-r)*xp*SCALE
            ptrdiff_t ho = hb + (ptrdiff_t)i * hstep;
            if (OUT_F32) Hf[ho] = h; else Hh[ho] = f2bf(h);
        }
    };

    u16x4 b0[PF], b1[PF];
    loadB(b0, 0);
    loadB(b1, 1);
    for (int t = 0; t < NB; t += 2) {
        compStore(b0, t);
        if (t + 2 < NB) loadB(b0, t + 2);
        compStore(b1, t + 1);
        if (t + 3 < NB) loadB(b1, t + 3);
    }

    if (OUT_F32) ((float*)Cv)[b * 1024 + ch] = c;
    else         ((u16*)Cv)[b * 1024 + ch]  = f2bf(c);
}

// ---------------- launch ----------------
extern "C" void kernel_launch(void* const* d_in, const int* in_sizes, int n_in,
                              void* d_out, int out_size, void* d_ws, size_t ws_size,
                              hipStream_t stream) {
    (void)in_sizes; (void)n_in; (void)out_size; (void)ws_size;

    const float* seqs = (const float*)d_in[0];
    const float* W0   = (const float*)d_in[1];
    const float* vf0  = (const float*)d_in[2];
    const float* vr0  = (const float*)d_in[3];
    const float* bf0  = (const float*)d_in[4];
    const float* br0  = (const float*)d_in[5];
    const float* W1   = (const float*)d_in[6];
    const float* vf1  = (const float*)d_in[7];
    const float* vr1  = (const float*)d_in[8];
    const float* bf1  = (const float*)d_in[9];
    const float* br1  = (const float*)d_in[10];
    // d_in[11] = lengths : unused by the reference

    float* out = (float*)d_out;  // [c1: 32*1024 f32][out1: 32*1024*1024 f32]
    char* ws = (char*)d_ws;

    const size_t U_BYTES  = (size_t)M_ * N8D * 2;        // 268435456
    const size_t H_BYTES  = (size_t)M_ * 1024 * 2;       // 67108864
    const size_t W0T_B    = (size_t)4096 * 512 * 2;      // 4194304
    const size_t W1T_B    = (size_t)4096 * 1024 * 2;     // 8388608

    u16* U   = (u16*)(ws);
    u16* H0  = (u16*)(ws + U_BYTES);               // also holds seqs_bf16 before scan0
    u16* S16 = H0;                                  // dead after gemm0
    u16* W0T = (u16*)(ws + U_BYTES + H_BYTES);
    u16* W1T = (u16*)(ws + U_BYTES + H_BYTES + W0T_B);
    u16* Cd  = (u16*)(ws + U_BYTES + H_BYTES + W0T_B + W1T_B);  // dummy c, layer 0

    // seqs f32 -> bf16
    f32_to_bf16<<<dim3(M_ * 512 / 8 / 256), 256, 0, stream>>>(seqs, S16);

    // W0 (512,4096) f32 -> W0T bf16 (permuted rows); W1 (1024,4096) -> W1T
    transpose_w<<<dim3(4096 / 32, 512 / 32), 256, 0, stream>>>(W0, W0T, 512, 4096);
    transpose_w<<<dim3(4096 / 32, 1024 / 32), 256, 0, stream>>>(W1, W1T, 1024, 4096);

    // Layer 0: A = seqs_bf16, K=512
    gemm_bt<<<dim3(N8D / 128, M_ / 128), 256, 0, stream>>>(S16, W0T, U, 512);
    sru_scan<false><<<dim3(M_ / 256), 256, 0, stream>>>(U, vf0, vr0, bf0, br0, (void*)H0, (void*)Cd);

    // Layer 1: A = H0 (bf16), K=1024
    gemm_bt<<<dim3(N8D / 128, M_ / 128), 256, 0, stream>>>(H0, W1T, U, 1024);
    sru_scan<true><<<dim3(M_ / 256), 256, 0, stream>>>(U, vf1, vr1, bf1, br1,
                                                       (void*)(out + B_ * 1024), (void*)out);
}